// Round 5
// baseline (15166.010 us; speedup 1.0000x reference)
//
#include <hip/hip_runtime.h>
#include <stdint.h>
#include <stddef.h>

// B=32 TENC=2048 LIS=512 HID=512 EMB=256 CLS=64 KEY=128 VAL=128 T=64 steps
// Outputs (f32, concat): logits [64,32,64] @0 ; preds.T [32,64] @131072 ; atts [64,32,2048] @133120
// Persistent kernel (plain launch), 256 blocks x 256 threads, hand-rolled agent-scope grid barrier.

struct P {
  const float* listener; const int* outlen; const int* ptgt;
  const float* embed;
  const float *W_ih1, *W_hh1, *b_ih1, *b_hh1;
  const float *W_ih2, *W_hh2, *b_ih2, *b_hh2;
  const float *W_s, *b_s, *W_h, *b_h, *W_v, *b_v, *W_c, *b_c;
  const float *h1_0, *c1_0, *h2_0, *c2_0;
  float* keyT;            // [32][128][2048] transposed key, f32
  float* value;           // [32][2048][128] f32
  float *h1a, *h1b, *c1;  // h1 ping-pong, c1 block-owned columns
  float *h2a, *c2a, *h2b, *c2b;
  float *gates2;          // [32][2048]
  float *wbuf;            // [32][2048] unnormalized att weights
  float *ctxnum;          // [32][128]
  float *Ssum;            // [32]
  int*   bar;             // [2] barrier {count, generation}
  float* out;
};

__device__ __forceinline__ float sigf(float x) { return 1.0f / (1.0f + expf(-x)); }

// grid barrier: counter+generation, agent scope (cross-XCD safe).
// Release chain: each block's s_waitcnt-drained stores -> ACQ_REL RMW on count;
// last arriver resets count, ACQ_REL-increments gen; spinners relaxed-poll gen
// then agent-acquire fence. All 256 blocks are resident (grid == CU count).
__device__ __forceinline__ void gsync(int* bar) {
  __syncthreads();
  if (threadIdx.x == 0) {
    int gen  = __hip_atomic_load(&bar[1], __ATOMIC_RELAXED, __HIP_MEMORY_SCOPE_AGENT);
    int prev = __hip_atomic_fetch_add(&bar[0], 1, __ATOMIC_ACQ_REL, __HIP_MEMORY_SCOPE_AGENT);
    if (prev == 255) {
      __hip_atomic_store(&bar[0], 0, __ATOMIC_RELAXED, __HIP_MEMORY_SCOPE_AGENT);
      __hip_atomic_fetch_add(&bar[1], 1, __ATOMIC_ACQ_REL, __HIP_MEMORY_SCOPE_AGENT);
    } else {
      while (__hip_atomic_load(&bar[1], __ATOMIC_RELAXED, __HIP_MEMORY_SCOPE_AGENT) == gen)
        __builtin_amdgcn_s_sleep(2);
    }
    __builtin_amdgcn_fence(__ATOMIC_ACQUIRE, "agent");
  }
  __syncthreads();
}

// exact jax threefry2x32 (20 rounds)
__device__ __forceinline__ void tf2x32(uint32_t k0, uint32_t k1,
                                       uint32_t x0, uint32_t x1,
                                       uint32_t& o0, uint32_t& o1) {
  uint32_t k2 = k0 ^ k1 ^ 0x1BD11BDAu;
#define TFR(r) { x0 += x1; x1 = (x1 << (r)) | (x1 >> (32 - (r))); x1 ^= x0; }
  x0 += k0; x1 += k1;
  TFR(13) TFR(15) TFR(26) TFR(6)   x0 += k1; x1 += k2 + 1u;
  TFR(17) TFR(29) TFR(16) TFR(24)  x0 += k2; x1 += k0 + 2u;
  TFR(13) TFR(15) TFR(26) TFR(6)   x0 += k0; x1 += k1 + 3u;
  TFR(17) TFR(29) TFR(16) TFR(24)  x0 += k1; x1 += k2 + 4u;
  TFR(13) TFR(15) TFR(26) TFR(6)   x0 += k2; x1 += k0 + 5u;
#undef TFR
  o0 = x0; o1 = x1;
}

__device__ __forceinline__ float gumbel_f(uint32_t bits) {
  float f = __uint_as_float((bits >> 9) | 0x3f800000u) - 1.0f;
  float u = (f == 0.0f) ? 1.17549435e-38f : f;
  return -logf(-logf(u));
}

// finalize step: logits + categorical sample for batches q and q+16 (q in [0,16))
__device__ void finalize_step(const P& p, int step, int q, float* smem) {
  float* xc = smem;          // [2][640]
  float* lg = smem + 1280;   // [2][64]
  const int tid = threadIdx.x;
  const float* h2p = (step & 1) ? p.h2b : p.h2a;
  for (int n = tid; n < 1280; n += 256) {
    int row = n / 640, k = n - row * 640;
    int b = row ? q + 16 : q;
    float v;
    if (k < 512) v = h2p[b * 512 + k];
    else         v = p.ctxnum[b * 128 + (k - 512)] / fmaxf(p.Ssum[b], 1e-12f);
    xc[row * 640 + k] = v;
  }
  __syncthreads();
  if (tid < 128) {
    int row = tid >> 6, c = tid & 63;
    int b = row ? q + 16 : q;
    const float* wr = p.W_c + c * 640;
    float acc = p.b_c[c];
    for (int k4 = 0; k4 < 160; ++k4) {
      float4 w4 = ((const float4*)wr)[k4];
      float4 x4 = ((const float4*)(xc + row * 640))[k4];
      acc = fmaf(w4.x, x4.x, fmaf(w4.y, x4.y, fmaf(w4.z, x4.z, fmaf(w4.w, x4.w, acc))));
    }
    lg[row * 64 + c] = acc;
    p.out[(size_t)(step * 32 + b) * 64 + c] = acc;
  }
  __syncthreads();
  if (tid < 64) {
    int c = tid;
    uint32_t n0, n1, a0, a1, b0, b1;
    tf2x32(0u, 2u, 0u, (uint32_t)step, n0, n1);   // fold_in(key(2), step)
    uint32_t pa = (uint32_t)(q * 64 + c);
    uint32_t pb = pa + 1024u;
    tf2x32(n0, n1, 0u, pa, a0, a1);
    tf2x32(n0, n1, 0u, pb, b0, b1);
    float z0 = gumbel_f(a0 ^ a1) + lg[c];
    float z1 = gumbel_f(b0 ^ b1) + lg[64 + c];
    int i0 = c, i1 = c;
    for (int off = 32; off; off >>= 1) {
      float zz = __shfl_xor(z0, off, 64); int ii = __shfl_xor(i0, off, 64);
      if (zz > z0 || (zz == z0 && ii < i0)) { z0 = zz; i0 = ii; }
      zz = __shfl_xor(z1, off, 64); ii = __shfl_xor(i1, off, 64);
      if (zz > z1 || (zz == z1 && ii < i1)) { z1 = zz; i1 = ii; }
    }
    if (c == 0) {
      p.out[131072 + q * 64 + step]        = (float)i0;
      p.out[131072 + (q + 16) * 64 + step] = (float)i1;
    }
  }
}

// S3: h2/c2 update + query + energies + Ssum/ctxnum partials. blk in [0,256): b=blk>>3, 256-t chunk.
__device__ void s3_attn(const P& p, int step, int blk, int tid, float* smem) {
  const int b = blk >> 3, ch = blk & 7, t0 = ch * 256;
  float* sh2  = smem;         // 512
  float* sq   = smem + 512;   // 128
  float* sw   = smem + 640;   // 256
  float* sctx = smem + 896;   // 256
  float* sred = smem + 1152;  // 256
  if (step == 0) {
    for (int j = tid; j < 512; j += 256) sh2[j] = p.h2a[b * 512 + j];
  } else {
    const float* c2p = (((step - 1) & 1) ? p.c2b : p.c2a) + b * 512;
    float* h2o = ((step & 1) ? p.h2b : p.h2a) + b * 512;
    float* c2o = ((step & 1) ? p.c2b : p.c2a) + b * 512;
    for (int j = tid; j < 512; j += 256) {
      float gi = p.gates2[b * 2048 + j];
      float gf = p.gates2[b * 2048 + 512 + j];
      float gg = p.gates2[b * 2048 + 1024 + j];
      float go = p.gates2[b * 2048 + 1536 + j];
      float c2n = sigf(gf) * c2p[j] + sigf(gi) * tanhf(gg);
      float h2n = sigf(go) * tanhf(c2n);
      sh2[j] = h2n;
      if (ch == 0) { h2o[j] = h2n; c2o[j] = c2n; }
    }
  }
  __syncthreads();
  if (tid < 128) {
    const float* wr = p.W_s + tid * 512;
    float a0 = 0.f, a1 = 0.f, a2 = 0.f, a3 = 0.f;
    for (int j4 = 0; j4 < 128; ++j4) {
      float4 w4 = ((const float4*)wr)[j4];
      float4 h4 = ((const float4*)sh2)[j4];
      a0 = fmaf(w4.x, h4.x, a0); a1 = fmaf(w4.y, h4.y, a1);
      a2 = fmaf(w4.z, h4.z, a2); a3 = fmaf(w4.w, h4.w, a3);
    }
    sq[tid] = p.b_s[tid] + ((a0 + a1) + (a2 + a3));
  }
  __syncthreads();
  const int len = p.outlen[b];
  {
    int t = t0 + tid;
    const float* kc = p.keyT + (size_t)b * 128 * 2048 + t;
    float e0 = 0.f, e1 = 0.f, e2 = 0.f, e3 = 0.f;
#pragma unroll 4
    for (int k = 0; k < 128; k += 4) {
      e0 = fmaf(kc[(k + 0) * 2048], sq[k + 0], e0);
      e1 = fmaf(kc[(k + 1) * 2048], sq[k + 1], e1);
      e2 = fmaf(kc[(k + 2) * 2048], sq[k + 2], e2);
      e3 = fmaf(kc[(k + 3) * 2048], sq[k + 3], e3);
    }
    float e = (e0 + e1) + (e2 + e3);
    bool m = (b == 0) || (t < len);
    float w = m ? expf(e) : 0.0f;
    p.wbuf[b * 2048 + t] = w;
    sw[tid] = w;
    sred[tid] = w;
  }
  __syncthreads();
  for (int s = 128; s > 0; s >>= 1) {
    if (tid < s) sred[tid] += sred[tid + s];
    __syncthreads();
  }
  if (tid == 0) atomicAdd(&p.Ssum[b], sred[0]);
  {
    int v = tid & 127, half = tid >> 7;
    const float* vb = p.value + ((size_t)b * 2048 + t0 + half * 128) * 128 + v;
    float a0 = 0.f, a1 = 0.f;
    for (int tt = 0; tt < 128; tt += 2) {
      a0 = fmaf(sw[half * 128 + tt], vb[tt * 128], a0);
      a1 = fmaf(sw[half * 128 + tt + 1], vb[(tt + 1) * 128], a1);
    }
    sctx[half * 128 + v] = a0 + a1;
  }
  __syncthreads();
  if (tid < 128) atomicAdd(&p.ctxnum[b * 128 + tid], sctx[tid] + sctx[128 + tid]);
}

// zero the grid-barrier state (d_ws is poisoned 0xAA before every call)
__global__ void k_zero(P p) {
  if (threadIdx.x < 2) p.bar[threadIdx.x] = 0;
}

__global__ void __launch_bounds__(256) k_speller(P p) {
  const int blk = blockIdx.x, tid = threadIdx.x;
  __shared__ __align__(16) float smem[8192];   // 32 KB, phase-multiplexed

  // ---- init ----
  if (blk < 64) {
    int idx = blk * 256 + tid;
    p.h1a[idx] = p.h1_0[idx];
    p.c1[idx]  = p.c1_0[idx];
    p.h2a[idx] = p.h2_0[idx];
    p.c2a[idx] = p.c2_0[idx];
  } else if (blk == 64) {
    for (int n = tid; n < 4096; n += 256) p.ctxnum[n] = 0.0f;
    if (tid < 32) p.Ssum[tid] = 0.0f;
  }
  gsync(p.bar);

  // ---- proj: key/value projections, 16 tiles per block ----
  for (int it = 0; it < 16; ++it) {
    const int tile = blk * 16 + it;
    const int b = tile >> 7, tb = tile & 127, t0 = tb * 16;
    const float* src = p.listener + ((size_t)b * 2048 + t0) * 512;
    for (int n = 0; n < 32; ++n) smem[n * 256 + tid] = src[n * 256 + tid];
    __syncthreads();
    const int c = tid;
    const float* wr = (c < 128) ? (p.W_h + c * 512) : (p.W_v + (c - 128) * 512);
    const float bias = (c < 128) ? p.b_h[c] : p.b_v[c - 128];
    float acc[16];
#pragma unroll
    for (int r = 0; r < 16; ++r) acc[r] = 0.0f;
    for (int k4 = 0; k4 < 128; ++k4) {
      float4 w4 = ((const float4*)wr)[k4];
#pragma unroll
      for (int r = 0; r < 16; ++r) {
        float4 x4 = ((const float4*)(smem + r * 512))[k4];
        acc[r] = fmaf(w4.x, x4.x, fmaf(w4.y, x4.y, fmaf(w4.z, x4.z, fmaf(w4.w, x4.w, acc[r]))));
      }
    }
    if (c < 128) {
#pragma unroll
      for (int r = 0; r < 16; ++r)
        p.keyT[((size_t)b * 128 + c) * 2048 + t0 + r] = acc[r] + bias;
    } else {
#pragma unroll
      for (int r = 0; r < 16; ++r)
        p.value[((size_t)b * 2048 + t0 + r) * 128 + (c - 128)] = acc[r] + bias;
    }
    __syncthreads();
  }
  gsync(p.bar);

  // ---- step 0 attention ----
  s3_attn(p, 0, blk, tid, smem);
  gsync(p.bar);

  for (int i = 1; i <= 64; ++i) {
    // ---- S1: gates1+act1 (blk<128) ; finalize(i-1) (128..143) ; atts(i-1) (144..255) ----
    if (blk < 128) {
      if (i < 64) {
        float* sx   = smem;                  // 32*132 = 4224
        float* invS = smem + 4224;           // 32
        int*   tokS = (int*)(smem + 4256);   // 32
        float* gbuf = smem + 4288;           // 16*32
        const int gl = tid >> 5, b = tid & 31;
        const int r0 = ((gl >> 2) * 512) + blk * 4 + (gl & 3);
        const int r1 = (((gl + 8) >> 2) * 512) + blk * 4 + ((gl + 8) & 3);
        if (tid < 32) {
          invS[tid] = 1.0f / fmaxf(p.Ssum[tid], 1e-12f);
          tokS[tid] = p.ptgt[tid * 65 + (i - 1)];
        }
        const float* h1r = (i & 1) ? p.h1a : p.h1b;   // h1 of step i-1
        float acc0 = 0.0f, acc1 = 0.0f;
        for (int kt = 0; kt < 7; ++kt) {   // K = 896
          __syncthreads();
          for (int n = 0; n < 16; ++n) {
            int idx = n * 256 + tid, fb = idx >> 7, kk = idx & 127;
            float v;
            if (kt < 2)       v = p.embed[tokS[fb] * 256 + kt * 128 + kk];
            else if (kt == 2) v = p.ctxnum[fb * 128 + kk] * invS[fb];
            else              v = h1r[fb * 512 + (kt - 3) * 128 + kk];
            sx[fb * 132 + kk] = v;
          }
          __syncthreads();
          const float *w0, *w1;
          if (kt < 3) { w0 = p.W_ih1 + r0 * 384 + kt * 128;       w1 = p.W_ih1 + r1 * 384 + kt * 128; }
          else        { w0 = p.W_hh1 + r0 * 512 + (kt - 3) * 128; w1 = p.W_hh1 + r1 * 512 + (kt - 3) * 128; }
          const float4* x4p = (const float4*)(sx + b * 132);
#pragma unroll
          for (int k4 = 0; k4 < 32; ++k4) {
            float4 x4 = x4p[k4];
            float4 a4 = ((const float4*)w0)[k4];
            float4 c4 = ((const float4*)w1)[k4];
            acc0 = fmaf(a4.x, x4.x, fmaf(a4.y, x4.y, fmaf(a4.z, x4.z, fmaf(a4.w, x4.w, acc0))));
            acc1 = fmaf(c4.x, x4.x, fmaf(c4.y, x4.y, fmaf(c4.z, x4.z, fmaf(c4.w, x4.w, acc1))));
          }
        }
        gbuf[gl * 32 + b]       = acc0 + p.b_ih1[r0] + p.b_hh1[r0];
        gbuf[(gl + 8) * 32 + b] = acc1 + p.b_ih1[r1] + p.b_hh1[r1];
        __syncthreads();
        if (tid < 128) {
          int bb = tid & 31, jj = tid >> 5;
          int j = blk * 4 + jj;
          float gi = gbuf[jj * 32 + bb];
          float gf = gbuf[(4 + jj) * 32 + bb];
          float gg = gbuf[(8 + jj) * 32 + bb];
          float go = gbuf[(12 + jj) * 32 + bb];
          float c = sigf(gf) * p.c1[bb * 512 + j] + sigf(gi) * tanhf(gg);
          float* h1w = (i & 1) ? p.h1b : p.h1a;
          h1w[bb * 512 + j] = sigf(go) * tanhf(c);
          p.c1[bb * 512 + j] = c;
        }
      }
    } else if (blk < 144) {
      finalize_step(p, i - 1, blk - 128, smem);
    } else {
      for (int n = (blk - 144) * 256 + tid; n < 65536; n += 112 * 256) {
        int b = n >> 11, t = n & 2047;
        float s = fmaxf(p.Ssum[b], 1e-12f);
        p.out[133120 + (size_t)((i - 1) * 32 + b) * 2048 + t] = p.wbuf[b * 2048 + t] / s;
      }
    }
    if (i == 64) break;
    gsync(p.bar);

    // ---- S2: gates2 (blk<128) ; blk 128 zeroes attn accumulators ----
    if (blk < 128) {
      float* sx = smem;
      const float* h1c = (i & 1) ? p.h1b : p.h1a;          // h1 of step i
      const float* h2p = ((i - 1) & 1) ? p.h2b : p.h2a;    // h2 of step i-1
      const int gl = tid >> 5, b = tid & 31;
      const int g0 = blk * 16 + gl, g1 = g0 + 8;
      float acc0 = 0.0f, acc1 = 0.0f;
      for (int kt = 0; kt < 8; ++kt) {  // K = 1024
        __syncthreads();
        for (int n = 0; n < 16; ++n) {
          int idx = n * 256 + tid, fb = idx >> 7, kk = idx & 127;
          float v = (kt < 4) ? h1c[fb * 512 + kt * 128 + kk]
                             : h2p[fb * 512 + (kt - 4) * 128 + kk];
          sx[fb * 132 + kk] = v;
        }
        __syncthreads();
        const float *w0, *w1;
        if (kt < 4) { w0 = p.W_ih2 + g0 * 512 + kt * 128;       w1 = p.W_ih2 + g1 * 512 + kt * 128; }
        else        { w0 = p.W_hh2 + g0 * 512 + (kt - 4) * 128; w1 = p.W_hh2 + g1 * 512 + (kt - 4) * 128; }
        const float4* x4p = (const float4*)(sx + b * 132);
#pragma unroll
        for (int k4 = 0; k4 < 32; ++k4) {
          float4 x4 = x4p[k4];
          float4 a4 = ((const float4*)w0)[k4];
          float4 c4 = ((const float4*)w1)[k4];
          acc0 = fmaf(a4.x, x4.x, fmaf(a4.y, x4.y, fmaf(a4.z, x4.z, fmaf(a4.w, x4.w, acc0))));
          acc1 = fmaf(c4.x, x4.x, fmaf(c4.y, x4.y, fmaf(c4.z, x4.z, fmaf(c4.w, x4.w, acc1))));
        }
      }
      p.gates2[b * 2048 + g0] = acc0 + p.b_ih2[g0] + p.b_hh2[g0];
      p.gates2[b * 2048 + g1] = acc1 + p.b_ih2[g1] + p.b_hh2[g1];
    } else if (blk == 128) {
      for (int n = tid; n < 4096; n += 256) p.ctxnum[n] = 0.0f;
      if (tid < 32) p.Ssum[tid] = 0.0f;
    }
    gsync(p.bar);

    // ---- S3: attention ----
    s3_attn(p, i, blk, tid, smem);
    gsync(p.bar);
  }
}

extern "C" void kernel_launch(void* const* d_in, const int* in_sizes, int n_in,
                              void* d_out, int out_size, void* d_ws, size_t ws_size,
                              hipStream_t stream) {
  P p;
  p.listener = (const float*)d_in[0];
  p.outlen   = (const int*)d_in[1];
  p.ptgt     = (const int*)d_in[2];
  // d_in[3] = teacher_forcing (==1 -> always teacher-forced)
  p.embed = (const float*)d_in[4];
  p.W_ih1 = (const float*)d_in[5];  p.W_hh1 = (const float*)d_in[6];
  p.b_ih1 = (const float*)d_in[7];  p.b_hh1 = (const float*)d_in[8];
  p.W_ih2 = (const float*)d_in[9];  p.W_hh2 = (const float*)d_in[10];
  p.b_ih2 = (const float*)d_in[11]; p.b_hh2 = (const float*)d_in[12];
  p.W_s = (const float*)d_in[13]; p.b_s = (const float*)d_in[14];
  p.W_h = (const float*)d_in[15]; p.b_h = (const float*)d_in[16];
  p.W_v = (const float*)d_in[17]; p.b_v = (const float*)d_in[18];
  p.W_c = (const float*)d_in[19]; p.b_c = (const float*)d_in[20];
  p.h1_0 = (const float*)d_in[21]; p.c1_0 = (const float*)d_in[22];
  p.h2_0 = (const float*)d_in[23]; p.c2_0 = (const float*)d_in[24];

  char* w = (char*)d_ws;
  p.keyT   = (float*)w; w += (size_t)32 * 128 * 2048 * 4;   // 32 MB
  p.value  = (float*)w; w += (size_t)32 * 2048 * 128 * 4;   // 32 MB
  p.h1a = (float*)w; w += 32 * 512 * 4;
  p.h1b = (float*)w; w += 32 * 512 * 4;
  p.c1  = (float*)w; w += 32 * 512 * 4;
  p.h2a = (float*)w; w += 32 * 512 * 4;
  p.c2a = (float*)w; w += 32 * 512 * 4;
  p.h2b = (float*)w; w += 32 * 512 * 4;
  p.c2b = (float*)w; w += 32 * 512 * 4;
  p.gates2 = (float*)w; w += 32 * 2048 * 4;
  p.wbuf   = (float*)w; w += 32 * 2048 * 4;
  p.ctxnum = (float*)w; w += 32 * 128 * 4;
  p.Ssum   = (float*)w; w += 32 * 4;
  p.bar    = (int*)w;   w += 2 * 4;
  p.out = (float*)d_out;

  k_zero<<<1, 64, 0, stream>>>(p);
  k_speller<<<256, 256, 0, stream>>>(p);
}